// Round 1
// baseline (381.398 us; speedup 1.0000x reference)
//
#include <hip/hip_runtime.h>
#include <math.h>

namespace {

constexpr int C_ = 3, T_ = 3000, F_ = 103, NB_ = 6;
constexpr int TT = 24;                       // t-steps per block; 3000/24 = 125 exact
constexpr int BS[NB_]  = {1, 10, 20, 30, 40, 61};   // band start bins (compile-time from _CFG)
constexpr int BNB[NB_] = {10, 11, 11, 11, 22, 16};  // band widths (e-s+1)
constexpr int BOF[NB_] = {0, 10, 21, 32, 43, 65};   // cumsum of BNB, total 81
constexpr int WTOT = 81 * 18;                // 1458 gaussian filter weights

__device__ __forceinline__ float softplus_(float x) {
  // jax.nn.softplus == logaddexp(x, 0) == max(x,0) + log1p(exp(-|x|))
  return fmaxf(x, 0.0f) + log1pf(expf(-fabsf(x)));
}
__device__ __forceinline__ float gelu_(float x) {
  return 0.5f * x * (1.0f + erff(x * 0.7071067811865475f));
}

__global__ __launch_bounds__(256)
void sleepband_kernel(const float* __restrict__ spec,
                      const float* __restrict__ centers,
                      const float* __restrict__ widths,
                      const float* __restrict__ gains,
                      const float* __restrict__ align_w,
                      const float* __restrict__ align_b,
                      const float* __restrict__ fc1_w,
                      const float* __restrict__ fc1_b,
                      const float* __restrict__ fc2_w,
                      const float* __restrict__ fc2_b,
                      const float* __restrict__ band_gain,
                      const float* __restrict__ gate_w,
                      const float* __restrict__ gate_b,
                      const float* __restrict__ proj_w,
                      const float* __restrict__ proj_b,
                      const float* __restrict__ bn_gamma,
                      const float* __restrict__ bn_beta,
                      const float* __restrict__ bn_mean,
                      const float* __restrict__ bn_var,
                      float* __restrict__ out)
{
  __shared__ float sSpec[C_][TT][105];   // pad 105: stride%32=9 (odd) -> conflict-free
  __shared__ float sBand[TT][109];       // 108 used, pad 109: stride%32=13 -> conflict-free
  __shared__ float sW[WTOT];             // gaussian filter weights [band][p=c*6+n][f]
  __shared__ float sAw[54], sAb[18], sF1[108], sF1b[6], sF2[108], sF2b[18],
                   sBg[6], sGw[9], sGb[3], sPw[9], sPb[3], sBnS[3], sBnO[3];

  const int tid = threadIdx.x;
  const int t0  = blockIdx.x * TT;
  const int b   = blockIdx.y;

  // ---------------- stage spec tile (fully coalesced) ----------------
  const float* specB = spec + (size_t)b * C_ * T_ * F_;
  for (int li = tid; li < C_ * TT * F_; li += 256) {
    int c   = li / (TT * F_);
    int rem = li - c * (TT * F_);
    int tt  = rem / F_;
    int f   = rem - tt * F_;
    sSpec[c][tt][f] = specB[(size_t)c * T_ * F_ + (size_t)(t0 + tt) * F_ + f];
  }

  // ---------------- stage small params ----------------
  if (tid < 54)  sAw[tid]  = align_w[tid];
  if (tid < 18)  sAb[tid]  = align_b[tid];
  if (tid < 108) sF1[tid]  = fc1_w[tid];
  if (tid < 6)   sF1b[tid] = fc1_b[tid];
  if (tid < 108) sF2[tid]  = fc2_w[tid];
  if (tid < 18)  sF2b[tid] = fc2_b[tid];
  if (tid < 6)   sBg[tid]  = band_gain[tid];
  if (tid < 9)   sGw[tid]  = gate_w[tid];
  if (tid < 3)   sGb[tid]  = gate_b[tid];
  if (tid < 9)   sPw[tid]  = proj_w[tid];
  if (tid < 3)   sPb[tid]  = proj_b[tid];
  if (tid < 3) {
    float sc = bn_gamma[tid] / sqrtf(bn_var[tid] + 1e-5f);
    sBnS[tid] = sc;
    sBnO[tid] = bn_beta[tid] - bn_mean[tid] * sc;
  }

  // ---------------- gaussian filter bank (per (band,c,n) = 108 tasks) ----------------
  if (tid < 108) {
    int i = tid / 18;                       // band
    int p = tid - i * 18;                   // c*6+n ; flat centers idx == tid
    int s = BS[i], nb = BNB[i];
    float mu = softplus_(centers[tid]) + (float)s;
    mu = fminf(fmaxf(mu, (float)s), (float)(s + nb - 1));
    float sd = softplus_(widths[tid]) + 0.001f;
    sd = fminf(fmaxf(sd, 0.5f), 2.0f * (float)nb / 6.0f);
    float sum = 0.0f;
    for (int f = 0; f < nb; ++f) {
      float d = ((float)f - mu) / sd;
      sum += expf(-0.5f * d * d);
    }
    float sc = gains[tid] / (sum + 1e-6f);
    float* wrow = &sW[BOF[i] * 18 + p * nb];
    for (int f = 0; f < nb; ++f) {
      float d = ((float)f - mu) / sd;
      wrow[f] = sc * expf(-0.5f * d * d);
    }
  }
  __syncthreads();

  // ---------------- Phase A: filt[b,c,t,n] = sum_f spec*w  (18*TT tasks) ----------------
  for (int task = tid; task < 18 * TT; task += 256) {
    int p  = task / TT;
    int tt = task - p * TT;
    int c  = p / 6;
    int n  = p - c * 6;
    #pragma unroll
    for (int i = 0; i < NB_; ++i) {
      const float* wrow = &sW[BOF[i] * 18 + p * BNB[i]];
      const float* srow = &sSpec[c][tt][BS[i]];
      float acc = 0.0f;
      #pragma unroll
      for (int f = 0; f < BNB[i]; ++f) acc += srow[f] * wrow[f];
      sBand[tt][(i * 3 + c) * 6 + n] = acc;
    }
  }
  __syncthreads();

  // ---------------- Phase B: align + attention + softmax + scale  (6*TT tasks) ----------------
  if (tid < 6 * TT) {
    int n  = tid / TT;
    int tt = tid - n * TT;
    float al[18];
    #pragma unroll
    for (int i = 0; i < 6; ++i) {
      float f0 = sBand[tt][(i * 3 + 0) * 6 + n];
      float f1 = sBand[tt][(i * 3 + 1) * 6 + n];
      float f2 = sBand[tt][(i * 3 + 2) * 6 + n];
      #pragma unroll
      for (int d = 0; d < 3; ++d)
        al[i * 3 + d] = sAw[i * 9 + d * 3 + 0] * f0 + sAw[i * 9 + d * 3 + 1] * f1 +
                        sAw[i * 9 + d * 3 + 2] * f2 + sAb[i * 3 + d];
    }
    float h[6];
    #pragma unroll
    for (int o = 0; o < 6; ++o) {
      float acc = sF1b[o];
      #pragma unroll
      for (int k = 0; k < 18; ++k) acc += sF1[o * 18 + k] * al[k];
      h[o] = gelu_(acc);
    }
    float at[18];
    #pragma unroll
    for (int k = 0; k < 18; ++k) {
      float acc = sF2b[k];
      #pragma unroll
      for (int o = 0; o < 6; ++o) acc += sF2[k * 6 + o] * h[o];
      at[k] = acc;
    }
    #pragma unroll
    for (int c = 0; c < 3; ++c) {
      float m = at[c];
      #pragma unroll
      for (int i = 1; i < 6; ++i) m = fmaxf(m, at[i * 3 + c]);
      float e[6], ssum = 0.0f;
      #pragma unroll
      for (int i = 0; i < 6; ++i) { e[i] = expf(at[i * 3 + c] - m); ssum += e[i]; }
      float inv = 1.0f / ssum;
      #pragma unroll
      for (int i = 0; i < 6; ++i)
        sBand[tt][(i * 3 + c) * 6 + n] = al[i * 3 + c] * (e[i] * inv) * sBg[i];
    }
  }
  __syncthreads();

  // ---------------- Phase C: upsample + gate + proj + BN + gelu  (TT*F tasks) ----------------
  for (int task = tid; task < TT * F_; task += 256) {
    int tt = task / F_;
    int f  = task - tt * F_;
    float enh0 = 0.0f, enh1 = 0.0f, enh2 = 0.0f;
    #pragma unroll
    for (int i = 0; i < NB_; ++i) {
      if (f >= BS[i] && f < BS[i] + BNB[i]) {
        int j = f - BS[i];
        float src = fmaxf(((float)j + 0.5f) * 6.0f / (float)BNB[i] - 0.5f, 0.0f);
        float x0f = floorf(src);
        int   x0  = (int)x0f;
        int   x1  = (x0 + 1 > 5) ? 5 : x0 + 1;
        float wl  = src - x0f;
        float om  = 1.0f - wl;
        enh0 += sBand[tt][(i * 3 + 0) * 6 + x0] * om + sBand[tt][(i * 3 + 0) * 6 + x1] * wl;
        enh1 += sBand[tt][(i * 3 + 1) * 6 + x0] * om + sBand[tt][(i * 3 + 1) * 6 + x1] * wl;
        enh2 += sBand[tt][(i * 3 + 2) * 6 + x0] * om + sBand[tt][(i * 3 + 2) * 6 + x1] * wl;
      }
    }
    float sv[3] = { sSpec[0][tt][f], sSpec[1][tt][f], sSpec[2][tt][f] };
    float rr[3] = { enh0 - sv[0], enh1 - sv[1], enh2 - sv[2] };
    float e2[3];
    #pragma unroll
    for (int d = 0; d < 3; ++d) {
      float gz = sGw[d * 3 + 0] * rr[0] + sGw[d * 3 + 1] * rr[1] + sGw[d * 3 + 2] * rr[2] + sGb[d];
      float gate = 1.0f / (1.0f + expf(-gz));
      e2[d] = sv[d] + gate * rr[d];
    }
    #pragma unroll
    for (int d = 0; d < 3; ++d) {
      float y = sPw[d * 3 + 0] * e2[0] + sPw[d * 3 + 1] * e2[1] + sPw[d * 3 + 2] * e2[2] + sPb[d];
      y = y * sBnS[d] + sBnO[d];
      out[((size_t)(b * C_ + d) * T_ + (size_t)(t0 + tt)) * F_ + f] = gelu_(y);
    }
  }
}

} // namespace

extern "C" void kernel_launch(void* const* d_in, const int* in_sizes, int n_in,
                              void* d_out, int out_size, void* d_ws, size_t ws_size,
                              hipStream_t stream) {
  (void)n_in; (void)out_size; (void)d_ws; (void)ws_size;
  const int B = in_sizes[0] / (C_ * T_ * F_);   // 64
  dim3 grid(T_ / TT, B);                        // (125, 64)
  sleepband_kernel<<<grid, 256, 0, stream>>>(
      (const float*)d_in[0],  (const float*)d_in[1],  (const float*)d_in[2],
      (const float*)d_in[3],  (const float*)d_in[4],  (const float*)d_in[5],
      (const float*)d_in[6],  (const float*)d_in[7],  (const float*)d_in[8],
      (const float*)d_in[9],  (const float*)d_in[10], (const float*)d_in[11],
      (const float*)d_in[12], (const float*)d_in[13], (const float*)d_in[14],
      (const float*)d_in[15], (const float*)d_in[16], (const float*)d_in[17],
      (const float*)d_in[18], (float*)d_out);
}

// Round 2
// 277.161 us; speedup vs baseline: 1.3761x; 1.3761x over previous
//
#include <hip/hip_runtime.h>
#include <math.h>

namespace {

constexpr int C_ = 3, T_ = 3000, F_ = 103, NB_ = 6;
constexpr int TT = 20;                       // t-steps per block; 3000/20 = 150 exact
constexpr int BS[NB_]  = {1, 10, 20, 30, 40, 61};   // band start bins (compile-time from _CFG)
constexpr int BNB[NB_] = {10, 11, 11, 11, 22, 16};  // band widths (e-s+1)
constexpr int BOF[NB_] = {0, 10, 21, 32, 43, 65};   // cumsum of BNB, total 81
constexpr int SPF = 81;                      // staged spec cols (bands span f=1..76)
constexpr int WTOT = 81 * 18;                // 1458 gaussian filter weights

__device__ __forceinline__ float softplus_(float x) {
  return fmaxf(x, 0.0f) + log1pf(expf(-fabsf(x)));
}
__device__ __forceinline__ float sigmoid_(float z) {
  return 1.0f / (1.0f + __expf(-z));
}
// tanh-approx gelu: 0.5x(1+tanh(0.79788456(x+0.044715x^3))) = x*sigmoid(1.5957691x(1+0.044715x^2))
__device__ __forceinline__ float gelu_(float x) {
  return x * sigmoid_(1.595769122f * x * (1.0f + 0.044715f * x * x));
}

__global__ __launch_bounds__(256)
void sleepband_kernel(const float* __restrict__ spec,
                      const float* __restrict__ centers,
                      const float* __restrict__ widths,
                      const float* __restrict__ gains,
                      const float* __restrict__ align_w,
                      const float* __restrict__ align_b,
                      const float* __restrict__ fc1_w,
                      const float* __restrict__ fc1_b,
                      const float* __restrict__ fc2_w,
                      const float* __restrict__ fc2_b,
                      const float* __restrict__ band_gain,
                      const float* __restrict__ gate_w,
                      const float* __restrict__ gate_b,
                      const float* __restrict__ proj_w,
                      const float* __restrict__ proj_b,
                      const float* __restrict__ bn_gamma,
                      const float* __restrict__ bn_beta,
                      const float* __restrict__ bn_mean,
                      const float* __restrict__ bn_var,
                      float* __restrict__ out)
{
  __shared__ float sSpec[C_][TT][SPF];   // stride 81 (%32=17, odd) -> conflict-free
  __shared__ float sBand[TT][109];       // 108 used, pad 109 (%32=13) -> conflict-free
  __shared__ float sW[WTOT];             // gaussian filter weights [band][p=c*6+n][f]
  __shared__ int   sTc[F_ * 5];          // interp tap col base (i*18+x), stride 5 pad
  __shared__ float sTw[F_ * 5];          // interp tap weight
  __shared__ float sAw[54], sAb[18], sF1[108], sF1b[6], sF2[108], sF2b[18],
                   sBg[6], sGw[9], sGb[3], sPw[9], sPb[3], sBnS[3], sBnO[3];

  const int tid = threadIdx.x;
  const int t0  = blockIdx.x * TT;
  const int b   = blockIdx.y;

  // ---------------- stage spec band region (coalesced) ----------------
  const float* specB = spec + (size_t)b * C_ * T_ * F_;
  for (int li = tid; li < C_ * TT * SPF; li += 256) {
    int c   = li / (TT * SPF);
    int rem = li - c * (TT * SPF);
    int tt  = rem / SPF;
    int f   = rem - tt * SPF;
    sSpec[c][tt][f] = specB[(size_t)c * T_ * F_ + (size_t)(t0 + tt) * F_ + f];
  }

  // ---------------- stage small params ----------------
  if (tid < 54)  sAw[tid]  = align_w[tid];
  if (tid < 18)  sAb[tid]  = align_b[tid];
  if (tid < 108) sF1[tid]  = fc1_w[tid];
  if (tid < 6)   sF1b[tid] = fc1_b[tid];
  if (tid < 108) sF2[tid]  = fc2_w[tid];
  if (tid < 18)  sF2b[tid] = fc2_b[tid];
  if (tid < 6)   sBg[tid]  = band_gain[tid];
  if (tid < 9)   sGw[tid]  = gate_w[tid];
  if (tid < 3)   sGb[tid]  = gate_b[tid];
  if (tid < 9)   sPw[tid]  = proj_w[tid];
  if (tid < 3)   sPb[tid]  = proj_b[tid];
  if (tid < 3) {
    float sc = bn_gamma[tid] / sqrtf(bn_var[tid] + 1e-5f);
    sBnS[tid] = sc;
    sBnO[tid] = bn_beta[tid] - bn_mean[tid] * sc;
  }

  // ---------------- gaussian filter bank (108 tasks, waves 0-1) ----------------
  if (tid < 108) {
    int i = tid / 18;                       // band
    int p = tid - i * 18;                   // c*6+n ; flat centers idx == tid
    int s = BS[i], nb = BNB[i];
    float mu = softplus_(centers[tid]) + (float)s;
    mu = fminf(fmaxf(mu, (float)s), (float)(s + nb - 1));
    float sd = softplus_(widths[tid]) + 0.001f;
    sd = fminf(fmaxf(sd, 0.5f), 2.0f * (float)nb / 6.0f);
    float sum = 0.0f;
    for (int f = 0; f < nb; ++f) {
      float d = ((float)f - mu) / sd;
      sum += __expf(-0.5f * d * d);
    }
    float sc = gains[tid] / (sum + 1e-6f);
    float* wrow = &sW[BOF[i] * 18 + p * nb];
    for (int f = 0; f < nb; ++f) {
      float d = ((float)f - mu) / sd;
      wrow[f] = sc * __expf(-0.5f * d * d);
    }
  }

  // ---------------- interp tap table (103 tasks, waves 2-3) ----------------
  if (tid >= 128 && tid < 128 + F_) {
    int f = tid - 128;
    int col[4] = {0, 0, 0, 0};
    float w[4] = {0.f, 0.f, 0.f, 0.f};
    int k = 0;
    #pragma unroll
    for (int i = 0; i < NB_; ++i) {
      if (f >= BS[i] && f < BS[i] + BNB[i]) {
        int j = f - BS[i];
        float src = fmaxf(((float)j + 0.5f) * 6.0f / (float)BNB[i] - 0.5f, 0.0f);
        float x0f = floorf(src);
        int   x0  = (int)x0f;
        int   x1  = (x0 + 1 > 5) ? 5 : x0 + 1;
        float wl  = src - x0f;
        col[k] = i * 18 + x0; w[k] = 1.0f - wl;
        col[k + 1] = i * 18 + x1; w[k + 1] = wl;
        k += 2;
      }
    }
    #pragma unroll
    for (int k2 = 0; k2 < 4; ++k2) { sTc[f * 5 + k2] = col[k2]; sTw[f * 5 + k2] = w[k2]; }
  }
  __syncthreads();

  // ---------------- Phase A: filt (18*TT tasks) ----------------
  for (int task = tid; task < 18 * TT; task += 256) {
    int p  = task / TT;
    int tt = task - p * TT;
    int c  = p / 6;
    int n  = p - c * 6;
    #pragma unroll
    for (int i = 0; i < NB_; ++i) {
      const float* wrow = &sW[BOF[i] * 18 + p * BNB[i]];
      const float* srow = &sSpec[c][tt][BS[i]];
      float acc = 0.0f;
      #pragma unroll
      for (int f = 0; f < BNB[i]; ++f) acc += srow[f] * wrow[f];
      sBand[tt][(i * 3 + c) * 6 + n] = acc;
    }
  }
  __syncthreads();

  // ---------------- Phase B: align + attention + softmax + scale (6*TT tasks) ----------------
  if (tid < 6 * TT) {
    int n  = tid / TT;
    int tt = tid - n * TT;
    float al[18];
    #pragma unroll
    for (int i = 0; i < 6; ++i) {
      float f0 = sBand[tt][(i * 3 + 0) * 6 + n];
      float f1 = sBand[tt][(i * 3 + 1) * 6 + n];
      float f2 = sBand[tt][(i * 3 + 2) * 6 + n];
      #pragma unroll
      for (int d = 0; d < 3; ++d)
        al[i * 3 + d] = sAw[i * 9 + d * 3 + 0] * f0 + sAw[i * 9 + d * 3 + 1] * f1 +
                        sAw[i * 9 + d * 3 + 2] * f2 + sAb[i * 3 + d];
    }
    float h[6];
    #pragma unroll
    for (int o = 0; o < 6; ++o) {
      float acc = sF1b[o];
      #pragma unroll
      for (int k = 0; k < 18; ++k) acc += sF1[o * 18 + k] * al[k];
      h[o] = gelu_(acc);
    }
    float at[18];
    #pragma unroll
    for (int k = 0; k < 18; ++k) {
      float acc = sF2b[k];
      #pragma unroll
      for (int o = 0; o < 6; ++o) acc += sF2[k * 6 + o] * h[o];
      at[k] = acc;
    }
    #pragma unroll
    for (int c = 0; c < 3; ++c) {
      float m = at[c];
      #pragma unroll
      for (int i = 1; i < 6; ++i) m = fmaxf(m, at[i * 3 + c]);
      float e[6], ssum = 0.0f;
      #pragma unroll
      for (int i = 0; i < 6; ++i) { e[i] = __expf(at[i * 3 + c] - m); ssum += e[i]; }
      float inv = 1.0f / ssum;
      #pragma unroll
      for (int i = 0; i < 6; ++i)
        sBand[tt][(i * 3 + c) * 6 + n] = al[i * 3 + c] * (e[i] * inv) * sBg[i];
    }
  }
  __syncthreads();

  // ---------------- Phase C: upsample (table) + gate + proj + BN + gelu ----------------
  for (int task = tid; task < TT * F_; task += 256) {
    int tt = task / F_;
    int f  = task - tt * F_;
    const float* brow = &sBand[tt][0];
    float enh0 = 0.0f, enh1 = 0.0f, enh2 = 0.0f;
    #pragma unroll
    for (int k = 0; k < 4; ++k) {
      int   cb = sTc[f * 5 + k];
      float w  = sTw[f * 5 + k];
      enh0 += brow[cb]      * w;
      enh1 += brow[cb + 6]  * w;
      enh2 += brow[cb + 12] * w;
    }
    const size_t gi = (size_t)(t0 + tt) * F_ + f;
    float sv[3] = { specB[gi], specB[(size_t)T_ * F_ + gi], specB[(size_t)2 * T_ * F_ + gi] };
    float rr[3] = { enh0 - sv[0], enh1 - sv[1], enh2 - sv[2] };
    float e2[3];
    #pragma unroll
    for (int d = 0; d < 3; ++d) {
      float gz = sGw[d * 3 + 0] * rr[0] + sGw[d * 3 + 1] * rr[1] + sGw[d * 3 + 2] * rr[2] + sGb[d];
      e2[d] = sv[d] + sigmoid_(gz) * rr[d];
    }
    #pragma unroll
    for (int d = 0; d < 3; ++d) {
      float y = sPw[d * 3 + 0] * e2[0] + sPw[d * 3 + 1] * e2[1] + sPw[d * 3 + 2] * e2[2] + sPb[d];
      y = y * sBnS[d] + sBnO[d];
      out[((size_t)(b * C_ + d) * T_) * F_ + gi] = gelu_(y);
    }
  }
}

} // namespace

extern "C" void kernel_launch(void* const* d_in, const int* in_sizes, int n_in,
                              void* d_out, int out_size, void* d_ws, size_t ws_size,
                              hipStream_t stream) {
  (void)n_in; (void)out_size; (void)d_ws; (void)ws_size;
  const int B = in_sizes[0] / (C_ * T_ * F_);   // 64
  dim3 grid(T_ / TT, B);                        // (150, 64)
  sleepband_kernel<<<grid, 256, 0, stream>>>(
      (const float*)d_in[0],  (const float*)d_in[1],  (const float*)d_in[2],
      (const float*)d_in[3],  (const float*)d_in[4],  (const float*)d_in[5],
      (const float*)d_in[6],  (const float*)d_in[7],  (const float*)d_in[8],
      (const float*)d_in[9],  (const float*)d_in[10], (const float*)d_in[11],
      (const float*)d_in[12], (const float*)d_in[13], (const float*)d_in[14],
      (const float*)d_in[15], (const float*)d_in[16], (const float*)d_in[17],
      (const float*)d_in[18], (float*)d_out);
}

// Round 3
// 246.910 us; speedup vs baseline: 1.5447x; 1.1225x over previous
//
#include <hip/hip_runtime.h>
#include <math.h>

namespace {

constexpr int C_ = 3, T_ = 3000, F_ = 103, NB_ = 6;
constexpr int TT = 20;                       // t-steps per block; 3000/20=150; TT*F%4==0
constexpr int BS[NB_]  = {1, 10, 20, 30, 40, 61};
constexpr int BNB[NB_] = {10, 11, 11, 11, 22, 16};
constexpr int BOF[NB_] = {0, 10, 21, 32, 43, 65};   // cumsum, total 81
constexpr int SPF = 81;                      // staged spec cols (bands span f=1..76)
constexpr int PLANE = T_ * F_;               // 309000
constexpr int SEC = 2064;                    // sEnh c-plane stride (2060 padded to x4)
constexpr int POOLN = 6320;                  // max(4860+1458, 3*2064)=6318 -> 6320

__device__ __forceinline__ float softplus_(float x) {
  return fmaxf(x, 0.0f) + log1pf(expf(-fabsf(x)));
}
__device__ __forceinline__ float sigmoid_(float z) {
  return 1.0f / (1.0f + __expf(-z));
}
__device__ __forceinline__ float gelu_(float x) {
  return x * sigmoid_(1.595769122f * x * (1.0f + 0.044715f * x * x));
}

__global__ __launch_bounds__(256)
void sleepband_kernel(const float* __restrict__ spec,
                      const float* __restrict__ centers,
                      const float* __restrict__ widths,
                      const float* __restrict__ gains,
                      const float* __restrict__ align_w,
                      const float* __restrict__ align_b,
                      const float* __restrict__ fc1_w,
                      const float* __restrict__ fc1_b,
                      const float* __restrict__ fc2_w,
                      const float* __restrict__ fc2_b,
                      const float* __restrict__ band_gain,
                      const float* __restrict__ gate_w,
                      const float* __restrict__ gate_b,
                      const float* __restrict__ proj_w,
                      const float* __restrict__ proj_b,
                      const float* __restrict__ bn_gamma,
                      const float* __restrict__ bn_beta,
                      const float* __restrict__ bn_mean,
                      const float* __restrict__ bn_var,
                      float* __restrict__ out)
{
  // Pool: [Phase A] sSpec[C][TT][81] (4860) + sW (1458)  ||  [B2/final] sEnh[3][SEC]
  __shared__ __align__(16) float sPool[POOLN];
  __shared__ float sBand[TT][109];       // 108 used, pad 109 (odd stride) -> conflict-free
  __shared__ float sAw[54], sAb[18], sF1[108], sF1b[6], sF2[108], sF2b[18],
                   sBg[6], sGw[9], sGb[3], sPw[9], sPb[3], sBnS[3], sBnO[3];

  const int tid = threadIdx.x;
  const int t0  = blockIdx.x * TT;
  const int b   = blockIdx.y;

  float* sW = sPool + C_ * TT * SPF;     // gaussian weights, Phase A only

  // ---------------- stage spec band region (coalesced) ----------------
  const float* specB = spec + (size_t)b * C_ * PLANE;
  for (int li = tid; li < C_ * TT * SPF; li += 256) {
    int c   = li / (TT * SPF);
    int rem = li - c * (TT * SPF);
    int tt  = rem / SPF;
    int f   = rem - tt * SPF;
    sPool[li] = specB[(size_t)c * PLANE + (size_t)(t0 + tt) * F_ + f];
  }

  // ---------------- stage small params ----------------
  if (tid < 54)  sAw[tid]  = align_w[tid];
  if (tid < 18)  sAb[tid]  = align_b[tid];
  if (tid < 108) sF1[tid]  = fc1_w[tid];
  if (tid < 6)   sF1b[tid] = fc1_b[tid];
  if (tid < 108) sF2[tid]  = fc2_w[tid];
  if (tid < 18)  sF2b[tid] = fc2_b[tid];
  if (tid < 6)   sBg[tid]  = band_gain[tid];
  if (tid < 9)   sGw[tid]  = gate_w[tid];
  if (tid < 3)   sGb[tid]  = gate_b[tid];
  if (tid < 9)   sPw[tid]  = proj_w[tid];
  if (tid < 3)   sPb[tid]  = proj_b[tid];
  if (tid < 3) {
    float sc = bn_gamma[tid] / sqrtf(bn_var[tid] + 1e-5f);
    sBnS[tid] = sc;
    sBnO[tid] = bn_beta[tid] - bn_mean[tid] * sc;
  }

  // ---------------- gaussian filter bank (108 tasks, waves 2-3) ----------------
  if (tid >= 128 && tid < 128 + 108) {
    int q = tid - 128;
    int i = q / 18;                       // band
    int p = q - i * 18;                   // c*6+n ; flat centers idx == q
    int s = BS[i], nb = BNB[i];
    float mu = softplus_(centers[q]) + (float)s;
    mu = fminf(fmaxf(mu, (float)s), (float)(s + nb - 1));
    float sd = softplus_(widths[q]) + 0.001f;
    sd = fminf(fmaxf(sd, 0.5f), 2.0f * (float)nb / 6.0f);
    float sum = 0.0f;
    for (int f = 0; f < nb; ++f) {
      float d = ((float)f - mu) / sd;
      sum += __expf(-0.5f * d * d);
    }
    float sc = gains[q] / (sum + 1e-6f);
    float* wrow = &sW[BOF[i] * 18 + p * nb];
    for (int f = 0; f < nb; ++f) {
      float d = ((float)f - mu) / sd;
      wrow[f] = sc * __expf(-0.5f * d * d);
    }
  }
  __syncthreads();

  // ---------------- Phase A: filt (18*TT=360 tasks) ----------------
  for (int task = tid; task < 18 * TT; task += 256) {
    int p  = task / TT;
    int tt = task - p * TT;
    int c  = p / 6;
    int n  = p - c * 6;
    const float* srowb = &sPool[(c * TT + tt) * SPF];
    #pragma unroll
    for (int i = 0; i < NB_; ++i) {
      const float* wrow = &sW[BOF[i] * 18 + p * BNB[i]];
      const float* srow = srowb + BS[i];
      float acc = 0.0f;
      #pragma unroll
      for (int f = 0; f < BNB[i]; ++f) acc += srow[f] * wrow[f];
      sBand[tt][(i * 3 + c) * 6 + n] = acc;
    }
  }
  __syncthreads();

  // ---------------- Phase B: align + attention + softmax + scale (6*TT tasks) ----------------
  if (tid < 6 * TT) {
    int n  = tid / TT;
    int tt = tid - n * TT;
    float al[18];
    #pragma unroll
    for (int i = 0; i < 6; ++i) {
      float f0 = sBand[tt][(i * 3 + 0) * 6 + n];
      float f1 = sBand[tt][(i * 3 + 1) * 6 + n];
      float f2 = sBand[tt][(i * 3 + 2) * 6 + n];
      #pragma unroll
      for (int d = 0; d < 3; ++d)
        al[i * 3 + d] = sAw[i * 9 + d * 3 + 0] * f0 + sAw[i * 9 + d * 3 + 1] * f1 +
                        sAw[i * 9 + d * 3 + 2] * f2 + sAb[i * 3 + d];
    }
    float h[6];
    #pragma unroll
    for (int o = 0; o < 6; ++o) {
      float acc = sF1b[o];
      #pragma unroll
      for (int k = 0; k < 18; ++k) acc += sF1[o * 18 + k] * al[k];
      h[o] = gelu_(acc);
    }
    float at[18];
    #pragma unroll
    for (int k = 0; k < 18; ++k) {
      float acc = sF2b[k];
      #pragma unroll
      for (int o = 0; o < 6; ++o) acc += sF2[k * 6 + o] * h[o];
      at[k] = acc;
    }
    #pragma unroll
    for (int c = 0; c < 3; ++c) {
      float m = at[c];
      #pragma unroll
      for (int i = 1; i < 6; ++i) m = fmaxf(m, at[i * 3 + c]);
      float e[6], ssum = 0.0f;
      #pragma unroll
      for (int i = 0; i < 6; ++i) { e[i] = __expf(at[i * 3 + c] - m); ssum += e[i]; }
      float inv = 1.0f / ssum;
      #pragma unroll
      for (int i = 0; i < 6; ++i)
        sBand[tt][(i * 3 + c) * 6 + n] = al[i * 3 + c] * (e[i] * inv) * sBg[i];
    }
  }
  __syncthreads();

  // ---------------- Phase B2: compile-time-tap upsample into dense sEnh ----------------
  // All taps (x0,x1,wl) fold to literals after unroll; band boundaries overlap by
  // exactly 1 bin -> carry the previous band's last-bin value.
  if (tid < C_ * TT) {
    const int c  = tid / TT;
    const int tt = tid - c * TT;
    float bnd[36];
    #pragma unroll
    for (int i = 0; i < 6; ++i)
      #pragma unroll
      for (int n = 0; n < 6; ++n)
        bnd[i * 6 + n] = sBand[tt][(i * 3 + c) * 6 + n];
    float* row = &sPool[c * SEC + tt * F_];
    row[0] = 0.0f;
    float carry = 0.0f;
    #pragma unroll
    for (int i = 0; i < NB_; ++i) {
      #pragma unroll
      for (int j = 0; j < BNB[i]; ++j) {
        float src = ((float)j + 0.5f) * 6.0f / (float)BNB[i] - 0.5f;
        src = src > 0.0f ? src : 0.0f;
        int   x0 = (int)src;
        int   x1 = (x0 < 5) ? x0 + 1 : 5;
        float wl = src - (float)x0;
        float v  = bnd[i * 6 + x0] * (1.0f - wl) + bnd[i * 6 + x1] * wl;
        if (j == 0) v += carry;
        if (i < NB_ - 1 && j == BNB[i] - 1) carry = v;
        else row[BS[i] + j] = v;
      }
    }
    #pragma unroll
    for (int f = 77; f < F_; ++f) row[f] = 0.0f;
  }
  __syncthreads();

  // ---------------- Final: flat float4 gate + proj + BN + gelu ----------------
  float gw[9], pw[9], gb3[3], pb3[3], bs3[3], bo3[3];
  #pragma unroll
  for (int k = 0; k < 9; ++k) { gw[k] = sGw[k]; pw[k] = sPw[k]; }
  #pragma unroll
  for (int k = 0; k < 3; ++k) { gb3[k] = sGb[k]; pb3[k] = sPb[k]; bs3[k] = sBnS[k]; bo3[k] = sBnO[k]; }

  const float* sp0 = specB + (size_t)t0 * F_;
  float* outB = out + (size_t)b * C_ * PLANE + (size_t)t0 * F_;
  for (int e4 = tid; e4 < (TT * F_) / 4; e4 += 256) {
    const int e = e4 * 4;
    const float4 sA = *(const float4*)(sp0 + e);
    const float4 sB = *(const float4*)(sp0 + PLANE + e);
    const float4 sC = *(const float4*)(sp0 + 2 * PLANE + e);
    const float4 eA = *(const float4*)&sPool[0 * SEC + e];
    const float4 eB = *(const float4*)&sPool[1 * SEC + e];
    const float4 eC = *(const float4*)&sPool[2 * SEC + e];
    float4 oA, oB, oC;
    const float* sAp = (const float*)&sA; const float* sBp = (const float*)&sB;
    const float* sCp = (const float*)&sC;
    const float* eAp = (const float*)&eA; const float* eBp = (const float*)&eB;
    const float* eCp = (const float*)&eC;
    float* oAp = (float*)&oA; float* oBp = (float*)&oB; float* oCp = (float*)&oC;
    #pragma unroll
    for (int j = 0; j < 4; ++j) {
      float sv0 = sAp[j], sv1 = sBp[j], sv2 = sCp[j];
      float r0 = eAp[j] - sv0, r1 = eBp[j] - sv1, r2 = eCp[j] - sv2;
      float e20 = sv0 + sigmoid_(gw[0] * r0 + gw[1] * r1 + gw[2] * r2 + gb3[0]) * r0;
      float e21 = sv1 + sigmoid_(gw[3] * r0 + gw[4] * r1 + gw[5] * r2 + gb3[1]) * r1;
      float e22 = sv2 + sigmoid_(gw[6] * r0 + gw[7] * r1 + gw[8] * r2 + gb3[2]) * r2;
      float y0 = (pw[0] * e20 + pw[1] * e21 + pw[2] * e22 + pb3[0]) * bs3[0] + bo3[0];
      float y1 = (pw[3] * e20 + pw[4] * e21 + pw[5] * e22 + pb3[1]) * bs3[1] + bo3[1];
      float y2 = (pw[6] * e20 + pw[7] * e21 + pw[8] * e22 + pb3[2]) * bs3[2] + bo3[2];
      oAp[j] = gelu_(y0); oBp[j] = gelu_(y1); oCp[j] = gelu_(y2);
    }
    *(float4*)(outB + e) = oA;
    *(float4*)(outB + PLANE + e) = oB;
    *(float4*)(outB + 2 * PLANE + e) = oC;
  }
}

} // namespace

extern "C" void kernel_launch(void* const* d_in, const int* in_sizes, int n_in,
                              void* d_out, int out_size, void* d_ws, size_t ws_size,
                              hipStream_t stream) {
  (void)n_in; (void)out_size; (void)d_ws; (void)ws_size;
  const int B = in_sizes[0] / (C_ * T_ * F_);   // 64
  dim3 grid(T_ / TT, B);                        // (150, 64)
  sleepband_kernel<<<grid, 256, 0, stream>>>(
      (const float*)d_in[0],  (const float*)d_in[1],  (const float*)d_in[2],
      (const float*)d_in[3],  (const float*)d_in[4],  (const float*)d_in[5],
      (const float*)d_in[6],  (const float*)d_in[7],  (const float*)d_in[8],
      (const float*)d_in[9],  (const float*)d_in[10], (const float*)d_in[11],
      (const float*)d_in[12], (const float*)d_in[13], (const float*)d_in[14],
      (const float*)d_in[15], (const float*)d_in[16], (const float*)d_in[17],
      (const float*)d_in[18], (float*)d_out);
}